// Round 3
// baseline (338.353 us; speedup 1.0000x reference)
//
#include <hip/hip_runtime.h>
#include <math.h>

// LiquidEchoHead, two-kernel split:
//   K1 (alpha_kernel):  per-row interference reduction -> alpha[row] in d_ws.
//                       Pure read-stream of x_real/x_imag + wave butterfly.
//   K2 (evolve_kernel): pure elementwise stream: blend with memory, one
//                       sincos on the summed angle, write outputs.
// Rationale: fused version measured 115us/dispatch at only 2.3 TB/s HBM with
// VALUBusy 12% -- the phase-coupled structure (load batch -> long serial
// sincos/reduce -> load batch) starves the memory system. Each split kernel
// is memcpy-shaped and independently profiled.
// Identity: cos(a)cos(b)-sin(a)sin(b)=cos(a+b); cos(a)sin(b)+sin(a)cos(b)=sin(a+b)
// -> evolution needs one sincos on (theta_r + theta_i).

#define PHI_F 1.61803398874989f

// Per-float4 interference accumulate step (K1 inner body).
__device__ __forceinline__ void k1_step(
    const float4* __restrict__ xr4, const float4* __restrict__ xi4,
    const float4* __restrict__ wq4, const float4* __restrict__ bq4,
    int c, float& aR, float& aI)
{
    float4 xr = xr4[c];
    float4 xi = xi4[c];
    float4 wq = wq4[c];
    float4 bq = bq4[c];
    #pragma unroll
    for (int j = 0; j < 4; ++j) {
        float xrv = (&xr.x)[j];
        float xiv = (&xi.x)[j];
        float wl  = 1.f + fabsf((&wq.x)[j]);
        float th  = xrv * __builtin_amdgcn_rcpf(wl) + (&bq.x)[j];
        float sq, cq;
        __sincosf(th, &sq, &cq);
        // interf_real += cq*xr + sq*xi ; interf_imag += cq*xi - sq*xr
        aR = fmaf(cq, xrv, fmaf(sq, xiv, aR));
        aI = fmaf(cq, xiv, fmaf(-sq, xrv, aI));
    }
}

// ---------------- K1: alpha per row (wave-per-row, 4 rows/block) -----------
__global__ __launch_bounds__(256) void alpha_kernel(
    const float* __restrict__ x_real, const float* __restrict__ x_imag,
    const float* __restrict__ w_query, const float* __restrict__ b_query,
    float* __restrict__ alpha_out,
    int d4, int B, float inv_scale)
{
    const int wave = (int)threadIdx.x >> 6;
    const int lane = (int)threadIdx.x & 63;
    const int row  = ((int)blockIdx.x << 2) + wave;
    if (row >= B) return;

    const size_t base4 = (size_t)row * d4;
    const float4* xr4 = (const float4*)x_real + base4;
    const float4* xi4 = (const float4*)x_imag + base4;
    const float4* wq4 = (const float4*)w_query;
    const float4* bq4 = (const float4*)b_query;

    float aR0 = 0.f, aI0 = 0.f;   // 2 accumulator pairs: break fma chain
    float aR1 = 0.f, aI1 = 0.f;

    if (d4 == 512) {
        // Bench shape (D=2048): fully unrolled, no guards -> compiler can
        // software-pipeline loads across all 8 chunks.
        #pragma unroll
        for (int s = 0; s < 8; ++s) {
            if (s & 1) k1_step(xr4, xi4, wq4, bq4, (s << 6) + lane, aR1, aI1);
            else       k1_step(xr4, xi4, wq4, bq4, (s << 6) + lane, aR0, aI0);
        }
    } else {
        for (int c = lane; c < d4; c += 64)
            k1_step(xr4, xi4, wq4, bq4, c, aR0, aI0);
    }

    float accR = aR0 + aR1;
    float accI = aI0 + aI1;

    // Butterfly: all 64 lanes end with the row totals. No LDS, no barrier.
    #pragma unroll
    for (int off = 32; off > 0; off >>= 1) {
        accR += __shfl_xor(accR, off);
        accI += __shfl_xor(accI, off);
    }

    if (lane == 0) {
        float interf = sqrtf(fmaf(accR, accR, accI * accI));
        float z      = fmaf(interf, inv_scale, -2.0f);
        float sig    = 1.f / (1.f + __expf(-z));   // sigmoid(z)
        alpha_out[row] = __expf(sig - 1.f);        // exp(-k*(1-sig)), k=1
    }
}

// ---------------- K2: elementwise evolution (block-per-row) ----------------
__global__ __launch_bounds__(256) void evolve_kernel(
    const float* __restrict__ x_real, const float* __restrict__ x_imag,
    const float* __restrict__ t_arr,
    const float* __restrict__ w_osc, const float* __restrict__ b_osc,
    const float* __restrict__ mem_r, const float* __restrict__ mem_i,
    const float* __restrict__ alpha_in,
    float* __restrict__ out_r, float* __restrict__ out_i,
    int d4)
{
    const int row = blockIdx.x;
    const float alpha = alpha_in[row];             // block-uniform scalar load
    const float beta  = 1.f - alpha;
    const float tphi2 = 2.0f * PHI_F * t_arr[row];

    const size_t base4 = (size_t)row * d4;
    const float4* xr4 = (const float4*)x_real + base4;
    const float4* xi4 = (const float4*)x_imag + base4;
    const float4* mr4 = (const float4*)mem_r + base4;
    const float4* mi4 = (const float4*)mem_i + base4;
    const float4* wo4 = (const float4*)w_osc;
    const float4* bo4 = (const float4*)b_osc;
    float4* or4 = (float4*)out_r + base4;
    float4* oi4 = (float4*)out_i + base4;

    for (int c = (int)threadIdx.x; c < d4; c += 256) {
        float4 xr = xr4[c];
        float4 xi = xi4[c];
        float4 mr = mr4[c];
        float4 mi = mi4[c];
        float4 wo = wo4[c];
        float4 bo = bo4[c];
        float4 oR, oI;
        #pragma unroll
        for (int j = 0; j < 4; ++j) {
            float br = fmaf(alpha, (&xr.x)[j], beta * (&mr.x)[j]);
            float bi = fmaf(alpha, (&xi.x)[j], beta * (&mi.x)[j]);
            float wl = 1.f + fabsf((&wo.x)[j]);
            float ang = fmaf(br + bi, __builtin_amdgcn_rcpf(wl),
                             fmaf(2.f, (&bo.x)[j], tphi2));
            float sv, cv;
            __sincosf(ang, &sv, &cv);
            (&oR.x)[j] = cv;   // evolved_real = cos(theta_r + theta_i)
            (&oI.x)[j] = sv;   // evolved_imag = sin(theta_r + theta_i)
        }
        or4[c] = oR;
        oi4[c] = oI;
    }
}

extern "C" void kernel_launch(void* const* d_in, const int* in_sizes, int n_in,
                              void* d_out, int out_size, void* d_ws, size_t ws_size,
                              hipStream_t stream) {
    const float* x_real   = (const float*)d_in[0];
    const float* x_imag   = (const float*)d_in[1];
    const float* t_arr    = (const float*)d_in[2];
    const float* w_query  = (const float*)d_in[3];
    const float* b_query  = (const float*)d_in[4];
    const float* w_osc    = (const float*)d_in[5];
    const float* b_osc    = (const float*)d_in[6];
    const float* mem_r    = (const float*)d_in[7];
    const float* mem_i    = (const float*)d_in[8];

    const int B = in_sizes[2];   // t is [B]
    const int D = in_sizes[3];   // w_query is [D]
    const int d4 = D >> 2;

    float* out_r = (float*)d_out;
    float* out_i = out_r + (size_t)B * D;
    float* alpha_ws = (float*)d_ws;   // B floats (32 KB at B=8192)

    const float inv_scale = 1.0f / sqrtf((float)D);

    const int grid1 = (B + 3) >> 2;          // 4 rows (waves) per block
    alpha_kernel<<<grid1, 256, 0, stream>>>(
        x_real, x_imag, w_query, b_query, alpha_ws, d4, B, inv_scale);

    evolve_kernel<<<B, 256, 0, stream>>>(
        x_real, x_imag, t_arr, w_osc, b_osc, mem_r, mem_i, alpha_ws,
        out_r, out_i, d4);
}